// Round 3
// baseline (241.310 us; speedup 1.0000x reference)
//
#include <hip/hip_runtime.h>
#include <stdint.h>

// LIF scan: u = 0.5*u + x_t; o = (u > 1); u = 0 where spiked. Bit-exact.
// x: [B=32, T=128, N=8192] fp32; out same, values in {0,1}.
//
// R10 (third submit of R8 -- R8/R9 benches died in container acquisition,
// no kernel signal; kernel audited: in-bounds, no barriers/LDS/atomics, no
// graph-capture violations): barrier-free streaming rewrite. R1-R7 fought
// vmcnt drains that exist only because of the LDS-ring structure
// (global_load_lds + s_barrier couples all waves; LDS staging has zero reuse
// here -- each x element is read once). New shape: each thread owns 4
// adjacent n-columns -> loads are naturally dwordx4 (16 B/lane sweet spot)
// straight to VGPRs. 16-deep per-thread register pipeline (static indices
// via full inner unroll), compiler emits counted vmcnt waits, no barrier
// anywhere, nothing ever drains to zero. Spikes stored per-t as
// fire-and-forget nontemporal dwordx4 (don't evict input from L3).
// 512 blocks x 128 thr, 0 LDS -> occupancy irrelevant (memory-bound;
// 16 KB/wave in flight, Little's law satisfied even at 1 wave/SIMD).

constexpr int B  = 32;
constexpr int T  = 128;
constexpr int N  = 8192;
constexpr int N4 = N / 4;            // 2048 float4 per (b,t) row
constexpr int THREADS = 128;
constexpr int SPAN4   = THREADS;     // float4 columns per block (512 floats)
constexpr int NTILES  = N4 / SPAN4;  // 16 n-tiles per batch row
constexpr int DP      = 16;          // pipeline depth in t-steps
constexpr int NG      = T / DP;      // 8 groups

typedef float v4f __attribute__((ext_vector_type(4)));

__device__ __forceinline__ float lif1(float& u, float x) {
    u = 0.5f * u + x;                 // 0.5*u exact -> fma == mul+add, bit-exact
    const bool s = u > 1.0f;
    const float o = s ? 1.0f : 0.0f;
    u = s ? 0.0f : u;                 // hard reset
    return o;
}

__device__ __forceinline__ void nt_store4(const float4& o, float4* p) {
    __builtin_nontemporal_store(*(const v4f*)&o, (v4f*)p);
}

__global__ __launch_bounds__(THREADS) void lif_kernel(const float4* __restrict__ x,
                                                      float4* __restrict__ out) {
    const int tid   = threadIdx.x;
    const int b     = blockIdx.x >> 4;             // NTILES = 16
    const int ntile = blockIdx.x & (NTILES - 1);
    const uint32_t base4 = (uint32_t)b * (T * N4) + (uint32_t)ntile * SPAN4 + tid;
    const float4* gx = x + base4;                  // stride N4 float4 per t
    float4*       go = out + base4;

    // prologue: fill the 16-deep pipe (16 independent dwordx4 in flight)
    float4 pipe[DP];
    #pragma unroll
    for (int k = 0; k < DP; ++k) pipe[k] = gx[(uint32_t)k * N4];

    float ux = 0.f, uy = 0.f, uz = 0.f, uw = 0.f;

    // main: consume pipe[k] for t=g*DP+k, immediately refill with t+DP.
    // Steady state: 16 loads + <=16 nt stores outstanding, compiler waits
    // counted vmcnt per use -- never 0, no barrier.
    #pragma unroll 1
    for (int g = 0; g < NG - 1; ++g) {
        const uint32_t roff = (uint32_t)(g + 1) * (DP * N4);
        const uint32_t woff = (uint32_t)g * (DP * N4);
        #pragma unroll
        for (int k = 0; k < DP; ++k) {
            const float4 v = pipe[k];
            pipe[k] = gx[roff + (uint32_t)k * N4];   // prefetch t + DP
            float4 o;
            o.x = lif1(ux, v.x);
            o.y = lif1(uy, v.y);
            o.z = lif1(uz, v.z);
            o.w = lif1(uw, v.w);
            nt_store4(o, go + woff + (uint32_t)k * N4);
        }
    }

    // epilogue group: no prefetch
    {
        const uint32_t woff = (uint32_t)(NG - 1) * (DP * N4);
        #pragma unroll
        for (int k = 0; k < DP; ++k) {
            const float4 v = pipe[k];
            float4 o;
            o.x = lif1(ux, v.x);
            o.y = lif1(uy, v.y);
            o.z = lif1(uz, v.z);
            o.w = lif1(uw, v.w);
            nt_store4(o, go + woff + (uint32_t)k * N4);
        }
    }
}

extern "C" void kernel_launch(void* const* d_in, const int* in_sizes, int n_in,
                              void* d_out, int out_size, void* d_ws, size_t ws_size,
                              hipStream_t stream) {
    const float4* x  = (const float4*)d_in[0];
    float4*      out = (float4*)d_out;
    lif_kernel<<<B * NTILES, THREADS, 0, stream>>>(x, out);   // 512 blocks
}

// Round 4
// 233.797 us; speedup vs baseline: 1.0321x; 1.0321x over previous
//
#include <hip/hip_runtime.h>
#include <stdint.h>

// LIF scan: u = 0.5*u + x_t; o = (u > 1); u = 0 where spiked. Bit-exact.
// x: [B=32, T=128, N=8192] fp32; out same, values in {0,1}.
//
// R11: max-TLP scalar streaming. R10 post-mortem: float4/thread caps the
// grid at 65536 threads = 1 wave/SIMD -> zero TLP; any vmcnt stall idles
// the SIMD (VALUBusy 5.7%, ~1500 cyc per t-step, 2.5 TB/s). Total chains
// = B*N = 262144, so vector width trades directly against wave count.
// This version: 1 float/thread -> 4096 waves = 16 waves/CU = 4 waves/SIMD
// (4x TLP), scalar dword loads still fully coalesced (256B/wave), 16-deep
// register pipe per thread unchanged (4 KB/wave in flight, 64 KB/CU).
// No LDS, no barriers, counted vmcnt from compiler, nt stores keep the
// output from evicting the L3-resident input (R10: FETCH halved to 64MB).

constexpr int B  = 32;
constexpr int T  = 128;
constexpr int N  = 8192;
constexpr int THREADS = 256;
constexpr int SPAN    = THREADS;     // floats per block = 256
constexpr int NTILES  = N / SPAN;    // 32 n-tiles per batch row
constexpr int DP      = 16;          // pipeline depth in t-steps
constexpr int NG      = T / DP;      // 8 groups

__global__ __launch_bounds__(THREADS) void lif_kernel(const float* __restrict__ x,
                                                      float* __restrict__ out) {
    const int tid   = threadIdx.x;
    const int b     = blockIdx.x >> 5;             // NTILES = 32
    const int ntile = blockIdx.x & (NTILES - 1);
    const uint32_t base = (uint32_t)b * (T * N) + (uint32_t)ntile * SPAN + tid;
    const float* gx = x + base;                    // stride N floats per t
    float*       go = out + base;

    // prologue: fill the 16-deep pipe (16 independent dword loads in flight)
    float pipe[DP];
    #pragma unroll
    for (int k = 0; k < DP; ++k) pipe[k] = gx[(uint32_t)k * N];

    float u = 0.f;

    // main: consume pipe[k] for t=g*DP+k, immediately refill with t+DP.
    // Static indices only (full unroll) so pipe stays in VGPRs.
    #pragma unroll 1
    for (int g = 0; g < NG - 1; ++g) {
        const uint32_t roff = (uint32_t)(g + 1) * (DP * N);
        const uint32_t woff = (uint32_t)g * (DP * N);
        #pragma unroll
        for (int k = 0; k < DP; ++k) {
            const float v = pipe[k];
            pipe[k] = gx[roff + (uint32_t)k * N];   // prefetch t + DP
            u = 0.5f * u + v;                       // bit-exact leak+integrate
            const bool s = u > 1.0f;
            __builtin_nontemporal_store(s ? 1.0f : 0.0f,
                                        go + woff + (uint32_t)k * N);
            u = s ? 0.0f : u;                       // hard reset
        }
    }

    // epilogue group: no prefetch
    {
        const uint32_t woff = (uint32_t)(NG - 1) * (DP * N);
        #pragma unroll
        for (int k = 0; k < DP; ++k) {
            const float v = pipe[k];
            u = 0.5f * u + v;
            const bool s = u > 1.0f;
            __builtin_nontemporal_store(s ? 1.0f : 0.0f,
                                        go + woff + (uint32_t)k * N);
            u = s ? 0.0f : u;
        }
    }
}

extern "C" void kernel_launch(void* const* d_in, const int* in_sizes, int n_in,
                              void* d_out, int out_size, void* d_ws, size_t ws_size,
                              hipStream_t stream) {
    const float* x   = (const float*)d_in[0];
    float*       out = (float*)d_out;
    lif_kernel<<<B * NTILES, THREADS, 0, stream>>>(x, out);   // 1024 blocks
}

// Round 5
// 231.978 us; speedup vs baseline: 1.0402x; 1.0078x over previous
//
#include <hip/hip_runtime.h>
#include <stdint.h>

// LIF scan: u = 0.5*u + x_t; o = (u > 1); u = 0 where spiked. Bit-exact.
// x: [B=32, T=128, N=8192] fp32; out same, values in {0,1}.
//
// R12: store-free scan + burst store, zero LDS/barriers.
// History: R7 (LDS ring + bitpack burst) ~70us; R10 (float4, 1 wave/SIMD)
// ~81us; R11 (scalar, 4 waves/SIMD, store-per-step) ~74us. All ~55-60% of
// the m13 mixed-copy ceiling (6.3 TB/s -> 42us floor).
// Theory: vmcnt retires IN ISSUE ORDER; R11 interleaved an nt store between
// every load, so each wait-for-load also waited for the slow write-ack of
// the store 16 steps back -- effective pipe depth collapsed. R7's own
// comment ("keeps stores out of vmcnt during the scan") was the right idea;
// its LDS ring + barriers were the dead weight. R12 = both fixes at once:
//   scan  = pure load stream, 16-deep register pipe, spikes bit-packed
//           into 4 u32 (fully unrolled -> all indices static, no scratch)
//   burst = 128 dependency-free coalesced nt stores (fill-like, 6.6 TB/s
//           capable at 9% occupancy per the fill kernel's own counters)
// 1024 blocks x 256 thr, 0 LDS, ~50 VGPR -> 16 waves/CU (4/SIMD) for TLP.

constexpr int B  = 32;
constexpr int T  = 128;
constexpr int N  = 8192;
constexpr int THREADS = 256;
constexpr int NTILES  = N / THREADS;   // 32 n-tiles per batch row
constexpr int DP      = 16;            // load pipeline depth in t-steps

__global__ __launch_bounds__(THREADS) void lif_kernel(const float* __restrict__ x,
                                                      float* __restrict__ out) {
    const int tid   = threadIdx.x;
    const int b     = blockIdx.x >> 5;              // NTILES = 32
    const int ntile = blockIdx.x & (NTILES - 1);
    const uint32_t base = (uint32_t)b * (T * N) + (uint32_t)ntile * THREADS + tid;
    const float* gx = x + base;                     // stride N floats per t
    float*       go = out + base;

    // prologue: fill the 16-deep pipe (16 independent dword loads in flight)
    float pipe[DP];
    #pragma unroll
    for (int k = 0; k < DP; ++k) pipe[k] = gx[(uint32_t)k * N];

    float u = 0.f;
    uint32_t sw0 = 0u, sw1 = 0u, sw2 = 0u, sw3 = 0u;   // 128 spike bits

    // scan: pure load stream -- no stores in the vmcnt window. Fully
    // unrolled so pipe[] and the sw selects are all compile-time static.
    #pragma unroll
    for (int t = 0; t < T; ++t) {
        const float v = pipe[t & (DP - 1)];
        if (t + DP < T)
            pipe[t & (DP - 1)] = gx[(uint32_t)(t + DP) * N];  // prefetch t+DP
        u = 0.5f * u + v;                       // bit-exact leak+integrate
        const bool s = u > 1.0f;
        const uint32_t bit = s ? 1u : 0u;
        if      (t <  32) sw0 |= bit << t;
        else if (t <  64) sw1 |= bit << (t - 32);
        else if (t <  96) sw2 |= bit << (t - 64);
        else              sw3 |= bit << (t - 96);
        u = s ? 0.0f : u;                       // hard reset
    }

    // burst: 128 independent coalesced 1 KB/wave nt stores, no deps.
    // nt keeps still-scanning blocks' x resident in L3.
    #pragma unroll
    for (int t = 0; t < T; ++t) {
        const uint32_t w = (t < 32) ? sw0 : (t < 64) ? sw1 : (t < 96) ? sw2 : sw3;
        const float sp = ((w >> (t & 31)) & 1u) ? 1.0f : 0.0f;
        __builtin_nontemporal_store(sp, go + (uint32_t)t * N);
    }
}

extern "C" void kernel_launch(void* const* d_in, const int* in_sizes, int n_in,
                              void* d_out, int out_size, void* d_ws, size_t ws_size,
                              hipStream_t stream) {
    const float* x   = (const float*)d_in[0];
    float*       out = (float*)d_out;
    lif_kernel<<<B * NTILES, THREADS, 0, stream>>>(x, out);   // 1024 blocks
}